// Round 3
// baseline (172.851 us; speedup 1.0000x reference)
//
#include <hip/hip_runtime.h>
#include <stdint.h>
#include <math.h>

// ---------------------------------------------------------------------------
// IID segmentation loss on MI355X.  Round 3.
//
// C[(n,dx)][(o,dy)] = sum_{b,y,x} xo[b,n,y,x+dx-7] * xt[b,o,y+7-dy,x]
// K1 restructured xc-outer / y-inner:
//   - B-frags live in REGISTERS, rotated across y by DPP row_shr:1
//     (lane l15 holds row y+7-l15; next y needs lane l15-1's row).
//     update_dpp(old=injected, src, 0x111) does rotate+inject in one op.
//     Fresh row y+8 injected into l15==0 lanes from global Bpad (4 lanes).
//   - A staged ONCE per block into LDS as 2 parity-shifted copies
//     (copy_c[i] = r[i+c]), so each A-frag = 4 aligned ds_read_b32
//     (compiler merges to ds_read2_b32). No alignbit in hot loop.
//   - ZERO barriers in the 1225-MFMA K-loop (2 staging barriers per block).
// Tail: reduce_stage1 vectorized float4; launches: prep_b, gemm, r1, rf, loss.
// ---------------------------------------------------------------------------

#define PADV 7
#define TS 15
#define KCLS 10
#define HH 224
#define WW 224
#define MD 160
#define NCELL (MD*MD)
#define NBLK 512
#define TY 7
#define BSTRIDE 232
#define BPH 240
#define LEPS 1e-16

typedef __attribute__((ext_vector_type(4))) float f32x4;
typedef __attribute__((ext_vector_type(8))) short bf16x8;

__device__ __forceinline__ unsigned short f2bf(float f) {
  union { float f; uint32_t u; } v; v.f = f;
  return (unsigned short)((v.u + 0x7FFFu + ((v.u >> 16) & 1u)) >> 16);
}

// Bpad[cls][yy][x]: cls=b*10+o, yy in [0,240) <-> row=yy-7, x in [0,232).
__global__ __launch_bounds__(256)
void prep_b(const float* __restrict__ xt, unsigned short* __restrict__ bp) {
  const int idx   = blockIdx.x * 256 + threadIdx.x;
  const int rowid = idx / 29;
  const int chunk = idx - rowid * 29;
  const int x0    = chunk * 8;
  const int yy    = rowid % BPH;
  const int cls   = rowid / BPH;
  const int row   = yy - PADV;
  union { unsigned short h[8]; uint4 v; } out;
  if (row >= 0 && row < HH && x0 < WW) {
    const float* src = xt + ((size_t)cls * HH + row) * WW + x0;
#pragma unroll
    for (int j = 0; j < 8; ++j) out.h[j] = f2bf(src[j]);
  } else {
    out.v = make_uint4(0u, 0u, 0u, 0u);
  }
  *(uint4*)(bp + (size_t)rowid * BSTRIDE + x0) = out.v;
}

// ---------------------------------------------------------------- K1: GEMM
__global__ __launch_bounds__(256, 2)
void corr_gemm(const float* __restrict__ xo, const unsigned short* __restrict__ bpad,
               float* __restrict__ partials) {
  // A in LDS: per (ry 0..6, cls 0..9): 480 elements = copy0[0..239] ++ copy1[0..239]
  // copy0[i] = xo[b,cls,y0+ry, i-7] (zero-padded), copy1[i] = copy0[i+1].
  __shared__ __align__(16) unsigned short ldsA[TY * KCLS * 480];  // 67200 B

  const int tid  = threadIdx.x;
  const int bid  = blockIdx.x;
  const int b    = bid >> 5;
  const int y0   = (bid & 31) * TY;

  const int lane = tid & 63;
  const int wv   = tid >> 6;
  const int wm   = wv & 1;
  const int wn   = wv >> 1;
  const int quad = lane >> 4;
  const int l15  = lane & 15;

  f32x4 acc[5][5];
#pragma unroll
  for (int i = 0; i < 5; ++i)
#pragma unroll
    for (int j = 0; j < 5; ++j) acc[i][j] = (f32x4){0.f, 0.f, 0.f, 0.f};

  const float* Ab = xo + (size_t)b * KCLS * HH * WW;

  // B-frag register state. bq[ni] = 4 dwords = 8 bf16.
  uint32_t bq[5][4], bnext[5][4], binj[5][4];
#pragma unroll
  for (int ni = 0; ni < 5; ++ni)
#pragma unroll
    for (int r = 0; r < 4; ++r) { bnext[ni][r] = 0; binj[ni][r] = 0; }

  // Initial B-frag prefetch for xc=0: lane l15 holds row y0+7-l15 -> yy=y0+14-l15.
  {
    int yy = y0 + 14 - l15;
    if (yy < 0) yy = 0;
#pragma unroll
    for (int ni = 0; ni < 5; ++ni) {
      const int cls = b * KCLS + wn * 5 + ni;
      const unsigned short* p = bpad + ((size_t)cls * BPH + yy) * BSTRIDE + quad * 8;
      *(uint4*)&bnext[ni][0] = *(const uint4*)p;
    }
  }

  // ---- staging phase 1: halo zeros + interior copy0 ----
  for (int t = tid; t < TY * KCLS * 16; t += 256) {
    const int rc = t >> 4;
    const int j  = t & 15;
    const int i  = (j < 7) ? j : (224 + j);     // i in {0..6} U {231..239}
    ldsA[rc * 480 + i] = 0;
  }
  for (int t = tid; t < TY * KCLS * 224; t += 256) {
    const int rc = t / 224;
    const int x  = t - rc * 224;
    const int ry = rc / KCLS;
    const int cl = rc - ry * KCLS;
    ldsA[rc * 480 + x + 7] =
        f2bf(Ab[((size_t)cl * HH + (y0 + ry)) * WW + x]);
  }
  __syncthreads();
  // ---- staging phase 2: build copy1 (copy1[i] = copy0[i+1]) ----
  {
    uint32_t* pw = (uint32_t*)ldsA;
    for (int t = tid; t < TY * KCLS * 30; t += 256) {
      const int rc = t / 30;
      const int ch = t - rc * 30;
      const uint32_t* src = pw + rc * 240 + ch * 4;
      uint32_t u0 = src[0], u1 = src[1], u2 = src[2], u3 = src[3];
      uint32_t u4 = (ch < 29) ? src[4] : 0u;
      union { uint32_t u[4]; uint4 v; } o;
      o.u[0] = __builtin_amdgcn_alignbit(u1, u0, 16);
      o.u[1] = __builtin_amdgcn_alignbit(u2, u1, 16);
      o.u[2] = __builtin_amdgcn_alignbit(u3, u2, 16);
      o.u[3] = __builtin_amdgcn_alignbit(u4, u3, 16);
      *(uint4*)(pw + rc * 240 + 120 + ch * 4) = o.v;
    }
  }
  __syncthreads();

  const uint32_t* lw = (const uint32_t*)ldsA;

  // ---- main loop: xc outer, y inner, barrier-free ----
#pragma unroll 1
  for (int xc = 0; xc < 7; ++xc) {
    const int x0 = xc * 32;
    // adopt prefetched init frags
#pragma unroll
    for (int ni = 0; ni < 5; ++ni)
#pragma unroll
      for (int r = 0; r < 4; ++r) bq[ni][r] = bnext[ni][r];

    const int e0   = x0 + quad * 8 + l15;
    const int c    = e0 & 1;
    const int wofs = c * 120 + ((e0 - c) >> 1);

#pragma unroll 1
    for (int iy = 0; iy < TY; ++iy) {
      // prefetches (consumed after this step's MFMAs)
      if (iy < TY - 1) {
        if (l15 == 0) {
          const int yy = y0 + iy + 15;   // row y+8 -> yy = y+15
#pragma unroll
          for (int ni = 0; ni < 5; ++ni) {
            const int cls = b * KCLS + wn * 5 + ni;
            const unsigned short* p =
                bpad + ((size_t)cls * BPH + yy) * BSTRIDE + x0 + quad * 8;
            *(uint4*)&binj[ni][0] = *(const uint4*)p;
          }
        }
      } else if (xc < 6) {
        int yy = y0 + 14 - l15;
        if (yy < 0) yy = 0;
#pragma unroll
        for (int ni = 0; ni < 5; ++ni) {
          const int cls = b * KCLS + wn * 5 + ni;
          const unsigned short* p =
              bpad + ((size_t)cls * BPH + yy) * BSTRIDE + (x0 + 32) + quad * 8;
          *(uint4*)&bnext[ni][0] = *(const uint4*)p;
        }
      }

      // A-frags: 4 aligned dword LDS reads per mi (parity-copy trick)
      bf16x8 afrag[5];
#pragma unroll
      for (int mi = 0; mi < 5; ++mi) {
        const int tm = wm * 5 + mi;
        const uint32_t* pa = lw + (iy * KCLS + tm) * 240 + wofs;
        union { uint32_t u[4]; bf16x8 v; } cv;
        cv.u[0] = pa[0]; cv.u[1] = pa[1]; cv.u[2] = pa[2]; cv.u[3] = pa[3];
        afrag[mi] = cv.v;
      }

#pragma unroll
      for (int mi = 0; mi < 5; ++mi)
#pragma unroll
        for (int ni = 0; ni < 5; ++ni) {
          union { uint32_t u[4]; bf16x8 v; } bv;
          bv.u[0] = bq[ni][0]; bv.u[1] = bq[ni][1];
          bv.u[2] = bq[ni][2]; bv.u[3] = bq[ni][3];
          acc[mi][ni] = __builtin_amdgcn_mfma_f32_16x16x32_bf16(
              afrag[mi], bv.v, acc[mi][ni], 0, 0, 0);
        }

      // rotate B-frags: lane l15 gets lane l15-1's frag; l15==0 gets inject.
      if (iy < TY - 1) {
#pragma unroll
        for (int ni = 0; ni < 5; ++ni)
#pragma unroll
          for (int r = 0; r < 4; ++r)
            bq[ni][r] = (uint32_t)__builtin_amdgcn_update_dpp(
                (int)binj[ni][r], (int)bq[ni][r], 0x111, 0xF, 0xF, false);
      }
    }
  }

  // C/D layout: col = lane&15, row = quad*4 + reg.
  float* outp = partials + (size_t)bid * NCELL;
#pragma unroll
  for (int mi = 0; mi < 5; ++mi)
#pragma unroll
    for (int ni = 0; ni < 5; ++ni) {
      const int mrow = (wm * 5 + mi) * 16 + quad * 4;
      const int ncol = (wn * 5 + ni) * 16 + l15;
#pragma unroll
      for (int r = 0; r < 4; ++r)
        outp[(size_t)(mrow + r) * MD + ncol] = acc[mi][ni][r];
    }
}

// --------------------------------------- K2a: reduce 512 -> 8 (float4)
__global__ __launch_bounds__(256)
void reduce_stage1(const float* __restrict__ partials, float* __restrict__ stage2) {
  const int pg = blockIdx.x / 25;            // 0..7
  const int cg = blockIdx.x - pg * 25;       // 0..24
  const int cb = cg * 1024 + threadIdx.x * 4;
  const float* base = partials + (size_t)pg * 64 * NCELL + cb;
  float4 s0 = {0,0,0,0}, s1 = {0,0,0,0}, s2 = {0,0,0,0}, s3 = {0,0,0,0};
  for (int p = 0; p < 64; p += 4) {
    float4 a = *(const float4*)(base + (size_t)(p + 0) * NCELL);
    float4 bb = *(const float4*)(base + (size_t)(p + 1) * NCELL);
    float4 cc = *(const float4*)(base + (size_t)(p + 2) * NCELL);
    float4 d = *(const float4*)(base + (size_t)(p + 3) * NCELL);
    s0.x += a.x; s0.y += a.y; s0.z += a.z; s0.w += a.w;
    s1.x += bb.x; s1.y += bb.y; s1.z += bb.z; s1.w += bb.w;
    s2.x += cc.x; s2.y += cc.y; s2.z += cc.z; s2.w += cc.w;
    s3.x += d.x; s3.y += d.y; s3.z += d.z; s3.w += d.w;
  }
  float4 o;
  o.x = (s0.x + s1.x) + (s2.x + s3.x);
  o.y = (s0.y + s1.y) + (s2.y + s3.y);
  o.z = (s0.z + s1.z) + (s2.z + s3.z);
  o.w = (s0.w + s1.w) + (s2.w + s3.w);
  *(float4*)(stage2 + (size_t)pg * NCELL + cb) = o;
}

// ------------------- K2f: 8 -> C (fp64) + block min + zero d_out
__global__ __launch_bounds__(256)
void reduce_final(const float* __restrict__ stage2, float* __restrict__ Cout,
                  float* __restrict__ mins, float* __restrict__ dout) {
  const int c = blockIdx.x * 256 + threadIdx.x;
  if (blockIdx.x == 0 && threadIdx.x == 0) dout[0] = 0.f;
  double s = 0.0;
#pragma unroll
  for (int pg = 0; pg < 8; ++pg) s += (double)stage2[(size_t)pg * NCELL + c];
  const float sf = (float)s;
  Cout[c] = sf;
  const int m  = c / MD;
  const int nn = c - m * MD;
  const bool valid = ((m & 15) < TS) && ((nn & 15) < TS);
  __shared__ float red[256];
  red[threadIdx.x] = valid ? sf : 3.4e38f;
  __syncthreads();
  for (int st = 128; st > 0; st >>= 1) {
    if (threadIdx.x < st)
      red[threadIdx.x] = fminf(red[threadIdx.x], red[threadIdx.x + st]);
    __syncthreads();
  }
  if (threadIdx.x == 0) mins[blockIdx.x] = red[0];
}

// ------------------- K4: per-shift loss (fp64), inline global min
__global__ __launch_bounds__(128)
void loss_kernel(const float* __restrict__ Cmat, const float* __restrict__ mins,
                 float* __restrict__ dout) {
  const int s   = blockIdx.x;
  const int dy  = s / TS;
  const int dx  = s - dy * TS;
  const int tid = threadIdx.x;
  __shared__ float fm[128];
  __shared__ double q[100];
  __shared__ double sym[100];
  __shared__ double pi[10], pj[10];
  __shared__ double red[128];

  fm[tid] = (tid < 100) ? mins[tid] : 3.4e38f;
  __syncthreads();
  for (int st = 64; st > 0; st >>= 1) {
    if (tid < st) fm[tid] = fminf(fm[tid], fm[tid + st]);
    __syncthreads();
  }
  const double minv = (double)fm[0];
  __syncthreads();

  if (tid < 100) {
    const int n = tid / 10, o = tid - (tid / 10) * 10;
    const double v = (double)Cmat[(size_t)(n * 16 + dx) * MD + (o * 16 + dy)];
    q[tid] = v - minv + LEPS;
  }
  __syncthreads();
  red[tid] = (tid < 100) ? q[tid] : 0.0;
  __syncthreads();
  for (int st = 64; st > 0; st >>= 1) {
    if (tid < st) red[tid] += red[tid + st];
    __syncthreads();
  }
  const double Z = red[0];
  __syncthreads();
  if (tid < 100) {
    const int n = tid / 10, o = tid - (tid / 10) * 10;
    sym[tid] = (q[n * 10 + o] + q[o * 10 + n]) * 0.5 / Z;
  }
  __syncthreads();
  if (tid < 10) {
    double a = 0.0, bsum = 0.0;
    for (int n2 = 0; n2 < 10; ++n2) {
      a    += sym[n2 * 10 + tid];
      bsum += sym[tid * 10 + n2];
    }
    pi[tid] = a;
    pj[tid] = bsum;
  }
  __syncthreads();
  double term = 0.0;
  if (tid < 100) {
    const int n = tid / 10, o = tid - (tid / 10) * 10;
    const double sp = sym[tid];
    term = -sp * (log(sp + LEPS) - log(pi[o] + LEPS) - log(pj[n] + LEPS));
  }
  red[tid] = term;
  __syncthreads();
  for (int st = 64; st > 0; st >>= 1) {
    if (tid < st) red[tid] += red[tid + st];
    __syncthreads();
  }
  if (tid == 0) atomicAdd(dout, (float)(red[0] / (double)(TS * TS)));
}

extern "C" void kernel_launch(void* const* d_in, const int* in_sizes, int n_in,
                              void* d_out, int out_size, void* d_ws, size_t ws_size,
                              hipStream_t stream) {
  const float* xo = (const float*)d_in[0];
  const float* xt = (const float*)d_in[1];
  float* ws       = (float*)d_ws;

  float* partials = ws;                                  // 512*25600 f32
  float* stage2   = partials + (size_t)NBLK * NCELL;     // 8*25600
  float* Cmat     = stage2 + (size_t)8 * NCELL;          // 25600
  float* mins     = Cmat + NCELL;                        // 100 (pad 128)
  unsigned short* bpad = (unsigned short*)(mins + 128);  // 160*240*232 bf16
  float* out      = (float*)d_out;

  hipLaunchKernelGGL(prep_b,        dim3(4350), dim3(256), 0, stream, xt, bpad);
  hipLaunchKernelGGL(corr_gemm,     dim3(NBLK), dim3(256), 0, stream, xo, bpad, partials);
  hipLaunchKernelGGL(reduce_stage1, dim3(200),  dim3(256), 0, stream, partials, stage2);
  hipLaunchKernelGGL(reduce_final,  dim3(100),  dim3(256), 0, stream, stage2, Cmat, mins, out);
  hipLaunchKernelGGL(loss_kernel,   dim3(225),  dim3(128), 0, stream, Cmat, mins, out);
}